// Round 4
// baseline (100.745 us; speedup 1.0000x reference)
//
#include <hip/hip_runtime.h>

#define P_POSES   32
#define A_ATOMS   4096
#define T_HASH    1048576
#define EPSF      1e-8f

typedef int   int4v  __attribute__((ext_vector_type(4)));
typedef float float3v __attribute__((ext_vector_type(3)));

__global__ void zero_out_kernel(float* __restrict__ out) {
    int i = threadIdx.x;
    if (i < P_POSES) out[i] = 0.0f;
}

// 12-byte vector load (global_load_dwordx3), 4-byte aligned
__device__ __forceinline__ float3v load_f3(const float* __restrict__ p) {
    float3v v;
    __builtin_memcpy(&v, p, 12);
    return v;
}

__global__ __launch_bounds__(256) void cartbonded_kernel(
    const float* __restrict__ coords,       // [P, A, 3]
    const float* __restrict__ hv,           // [T, 3]
    const int4v* __restrict__ atoms,        // [S, 4]
    const int*   __restrict__ pose,         // [S]
    const int*   __restrict__ uids,         // [P, A]
    float*       __restrict__ out,          // [P]
    int S)
{
    __shared__ float bins[P_POSES];
    if (threadIdx.x < P_POSES) bins[threadIdx.x] = 0.0f;
    __syncthreads();

    const int s = blockIdx.x * blockDim.x + threadIdx.x;
    if (s < S) {
        const int4v a = __builtin_nontemporal_load(&atoms[s]);
        const int   p = __builtin_nontemporal_load(&pose[s]);

        const bool v0 = a.x >= 0, v1 = a.y >= 0, v2 = a.z >= 0, v3 = a.w >= 0;
        const int  i0 = v0 ? a.x : 0;
        const int  i1 = v1 ? a.y : 0;
        const int  i2 = v2 ? a.z : 0;
        const int  i3 = v3 ? a.w : 0;
        const int  nv = (int)v0 + (int)v1 + (int)v2 + (int)v3;

        // uid gathers (L2-resident, 512 KB)
        const int* __restrict__ urow = uids + p * A_ATOMS;
        const unsigned int u0 = v0 ? (unsigned int)urow[i0] : 0u;
        const unsigned int u1 = v1 ? (unsigned int)urow[i1] : 0u;
        const unsigned int u2 = v2 ? (unsigned int)urow[i2] : 0u;
        const unsigned int u3 = v3 ? (unsigned int)urow[i3] : 0u;

        // coord gathers: one dwordx3 per point (independent of uids)
        const float* __restrict__ crow = coords + (size_t)p * (A_ATOMS * 3);
        const float3v P0 = load_f3(crow + i0 * 3);
        const float3v P1 = load_f3(crow + i1 * 3);
        const float3v P2 = load_f3(crow + i2 * 3);
        const float3v P3 = load_f3(crow + i3 * 3);

        // hash key -> one dwordx3 gather from hv
        const unsigned int key = (u0 + u1 + u2 + u3) & (unsigned int)(T_HASH - 1);
        const float3v H = load_f3(hv + (size_t)key * 3);
        const float K = H.x, x0 = H.y, period = H.z;

        // ---- bond
        const float dbx = P1.x - P0.x, dby = P1.y - P0.y, dbz = P1.z - P0.z;
        const float d  = sqrtf(dbx*dbx + dby*dby + dbz*dbz + EPSF);
        const float db = d - x0;
        const float e_bond = K * db * db;

        // ---- angle (u = p0-p1, v = p2-p1)
        const float ux = -dbx, uy = -dby, uz = -dbz;
        const float vx = P2.x - P1.x, vy = P2.y - P1.y, vz = P2.z - P1.z;
        const float uv = ux*vx + uy*vy + uz*vz;
        const float uu = ux*ux + uy*uy + uz*uz;
        const float vv = vx*vx + vy*vy + vz*vz;
        float cosang = uv / (sqrtf(uu + EPSF) * sqrtf(vv + EPSF));
        cosang = fminf(fmaxf(cosang, -0.999999f), 0.999999f);
        const float theta = acosf(cosang);
        const float da = theta - x0;
        const float e_angle = K * da * da;

        // ---- torsion
        const float b1x = dbx, b1y = dby, b1z = dbz;
        const float b2x = vx, b2y = vy, b2z = vz;
        const float b3x = P3.x - P2.x, b3y = P3.y - P2.y, b3z = P3.z - P2.z;
        const float n1x = b1y*b2z - b1z*b2y;
        const float n1y = b1z*b2x - b1x*b2z;
        const float n1z = b1x*b2y - b1y*b2x;
        const float n2x = b2y*b3z - b2z*b3y;
        const float n2y = b2z*b3x - b2x*b3z;
        const float n2z = b2x*b3y - b2y*b3x;
        const float b2inv = 1.0f / sqrtf(b2x*b2x + b2y*b2y + b2z*b2z + EPSF);
        const float bnx = b2x*b2inv, bny = b2y*b2inv, bnz = b2z*b2inv;
        const float m1x = n1y*bnz - n1z*bny;
        const float m1y = n1z*bnx - n1x*bnz;
        const float m1z = n1x*bny - n1y*bnx;
        const float sy = m1x*n2x + m1y*n2y + m1z*n2z;
        const float sx = n1x*n2x + n1y*n2y + n1z*n2z + EPSF;
        const float phi = atan2f(sy, sx);
        const float e_tors = K * (1.0f + cosf(period*phi - x0));

        const float e = (nv == 2) ? e_bond : ((nv == 3) ? e_angle : e_tors);
        atomicAdd(&bins[p], e);
    }

    __syncthreads();
    if (threadIdx.x < P_POSES) {
        const float b = bins[threadIdx.x];
        if (b != 0.0f) atomicAdd(&out[threadIdx.x], b);
    }
}

extern "C" void kernel_launch(void* const* d_in, const int* in_sizes, int n_in,
                              void* d_out, int out_size, void* d_ws, size_t ws_size,
                              hipStream_t stream) {
    const float* coords = (const float*)d_in[0];
    const float* hv     = (const float*)d_in[1];
    const int4v* atoms  = (const int4v*)d_in[2];
    const int*   pose   = (const int*)d_in[3];
    const int*   uids   = (const int*)d_in[4];
    float* out = (float*)d_out;

    const int S = in_sizes[3];   // subgraph_pose element count

    zero_out_kernel<<<1, 64, 0, stream>>>(out);

    const int block = 256;
    const int grid  = (S + block - 1) / block;
    cartbonded_kernel<<<grid, block, 0, stream>>>(coords, hv, atoms, pose, uids, out, S);
}

// Round 5
// 97.447 us; speedup vs baseline: 1.0338x; 1.0338x over previous
//
#include <hip/hip_runtime.h>

#define P_POSES   32
#define A_ATOMS   4096
#define T_HASH    1048576
#define EPSF      1e-8f
#define KSUB      16        // blocks per pose in main kernel (grid = 32*KSUB)
#define K3ITER    8
#define CHUNK     (K3ITER*256)

typedef int   int4v   __attribute__((ext_vector_type(4)));
typedef float float4v __attribute__((ext_vector_type(4)));

// ---------------- pass 1: histogram poses ----------------
__global__ __launch_bounds__(256) void k1_hist(const int* __restrict__ pose,
                                               int* __restrict__ counts, int S) {
    __shared__ int h[P_POSES];
    if (threadIdx.x < P_POSES) h[threadIdx.x] = 0;
    __syncthreads();
    const int stride = gridDim.x * blockDim.x;
    for (int s = blockIdx.x * blockDim.x + threadIdx.x; s < S; s += stride)
        atomicAdd(&h[__builtin_nontemporal_load(&pose[s])], 1);
    __syncthreads();
    if (threadIdx.x < P_POSES) atomicAdd(&counts[threadIdx.x], h[threadIdx.x]);
}

// ---------------- pass 2: exclusive scan (32 bins) ----------------
__global__ void k2_scan(const int* __restrict__ counts,
                        int* __restrict__ start, int* __restrict__ cursor) {
    const int lane = threadIdx.x;               // single wave of 64
    int c = (lane < P_POSES) ? counts[lane] : 0;
    int x = c;
    #pragma unroll
    for (int d = 1; d < 32; d <<= 1) {
        int y = __shfl_up(x, d, 64);
        if (lane >= d) x += y;
    }
    if (lane < P_POSES) { start[lane] = x - c; cursor[lane] = x - c; }
    if (lane == 31)     { start[P_POSES] = x; }
}

// ---------------- pass 3: scatter atoms into pose buckets ----------------
__global__ __launch_bounds__(256) void k3_scatter(const int*   __restrict__ pose,
                                                  const int4v* __restrict__ atoms,
                                                  int*   __restrict__ cursor,
                                                  int4v* __restrict__ sorted, int S) {
    __shared__ int cnt[P_POSES];
    __shared__ int base[P_POSES];
    const int tid = threadIdx.x;
    if (tid < P_POSES) cnt[tid] = 0;
    __syncthreads();

    int4v abuf[K3ITER];
    int   pbuf[K3ITER];
    int   rbuf[K3ITER];
    bool  actb[K3ITER];
    const int s0 = blockIdx.x * CHUNK;

    #pragma unroll
    for (int it = 0; it < K3ITER; ++it) {
        const int s = s0 + it * 256 + tid;
        actb[it] = s < S;
        if (actb[it]) {
            pbuf[it] = __builtin_nontemporal_load(&pose[s]);
            abuf[it] = __builtin_nontemporal_load(&atoms[s]);
            rbuf[it] = atomicAdd(&cnt[pbuf[it]], 1);
        }
    }
    __syncthreads();
    if (tid < P_POSES) base[tid] = atomicAdd(&cursor[tid], cnt[tid]);
    __syncthreads();
    #pragma unroll
    for (int it = 0; it < K3ITER; ++it)
        if (actb[it]) sorted[base[pbuf[it]] + rbuf[it]] = abuf[it];
}

// ---------------- pass 4: per-pose scoring with LDS-staged tables ----------------
__global__ __launch_bounds__(256, 2) void k4_main(const float* __restrict__ coords,
                                                  const float* __restrict__ hv,
                                                  const int*   __restrict__ uids,
                                                  const int*   __restrict__ start,
                                                  const int4v* __restrict__ sorted,
                                                  float*       __restrict__ out) {
    __shared__ float sC[A_ATOMS * 3];   // 48 KB
    __shared__ int   sU[A_ATOMS];       // 16 KB  (total exactly 64 KB)

    const int pose = blockIdx.x / KSUB;
    const int sub  = blockIdx.x % KSUB;
    const int tid  = threadIdx.x;

    {   // coalesced staging: coords row (3072 float4) + uids row (1024 int4)
        const float4v* src = (const float4v*)(coords + (size_t)pose * (A_ATOMS * 3));
        float4v* dst = (float4v*)sC;
        #pragma unroll 4
        for (int i = tid; i < (A_ATOMS * 3) / 4; i += 256) dst[i] = src[i];
        const int4v* usrc = (const int4v*)(uids + pose * A_ATOMS);
        int4v* udst = (int4v*)sU;
        for (int i = tid; i < A_ATOMS / 4; i += 256) udst[i] = usrc[i];
    }
    __syncthreads();

    const int s0 = start[pose], s1 = start[pose + 1];
    float esum = 0.0f;

    for (int i = s0 + sub * 256 + tid; i < s1; i += KSUB * 256) {
        const int4v a = __builtin_nontemporal_load(&sorted[i]);

        const bool v0 = a.x >= 0, v1 = a.y >= 0, v2 = a.z >= 0, v3 = a.w >= 0;
        const int  i0 = v0 ? a.x : 0;
        const int  i1 = v1 ? a.y : 0;
        const int  i2 = v2 ? a.z : 0;
        const int  i3 = v3 ? a.w : 0;
        const int  nv = (int)v0 + (int)v1 + (int)v2 + (int)v3;

        unsigned int key = 0u;
        key += v0 ? (unsigned int)sU[i0] : 0u;
        key += v1 ? (unsigned int)sU[i1] : 0u;
        key += v2 ? (unsigned int)sU[i2] : 0u;
        key += v3 ? (unsigned int)sU[i3] : 0u;
        key &= (unsigned int)(T_HASH - 1);

        const float K      = hv[3 * (size_t)key + 0];
        const float x0     = hv[3 * (size_t)key + 1];
        const float period = hv[3 * (size_t)key + 2];

        const float p0x = sC[3*i0+0], p0y = sC[3*i0+1], p0z = sC[3*i0+2];
        const float p1x = sC[3*i1+0], p1y = sC[3*i1+1], p1z = sC[3*i1+2];
        const float p2x = sC[3*i2+0], p2y = sC[3*i2+1], p2z = sC[3*i2+2];
        const float p3x = sC[3*i3+0], p3y = sC[3*i3+1], p3z = sC[3*i3+2];

        // bond
        const float dbx = p1x - p0x, dby = p1y - p0y, dbz = p1z - p0z;
        const float d  = sqrtf(dbx*dbx + dby*dby + dbz*dbz + EPSF);
        const float db = d - x0;
        const float e_bond = K * db * db;

        // angle (u = p0-p1, v = p2-p1)
        const float ux = -dbx, uy = -dby, uz = -dbz;
        const float vx = p2x - p1x, vy = p2y - p1y, vz = p2z - p1z;
        const float uv = ux*vx + uy*vy + uz*vz;
        const float uu = ux*ux + uy*uy + uz*uz;
        const float vv = vx*vx + vy*vy + vz*vz;
        float cosang = uv / (sqrtf(uu + EPSF) * sqrtf(vv + EPSF));
        cosang = fminf(fmaxf(cosang, -0.999999f), 0.999999f);
        const float theta = acosf(cosang);
        const float da = theta - x0;
        const float e_angle = K * da * da;

        // torsion
        const float b1x = dbx, b1y = dby, b1z = dbz;
        const float b2x = vx,  b2y = vy,  b2z = vz;
        const float b3x = p3x - p2x, b3y = p3y - p2y, b3z = p3z - p2z;
        const float n1x = b1y*b2z - b1z*b2y;
        const float n1y = b1z*b2x - b1x*b2z;
        const float n1z = b1x*b2y - b1y*b2x;
        const float n2x = b2y*b3z - b2z*b3y;
        const float n2y = b2z*b3x - b2x*b3z;
        const float n2z = b2x*b3y - b2y*b3x;
        const float b2inv = 1.0f / sqrtf(b2x*b2x + b2y*b2y + b2z*b2z + EPSF);
        const float bnx = b2x*b2inv, bny = b2y*b2inv, bnz = b2z*b2inv;
        const float m1x = n1y*bnz - n1z*bny;
        const float m1y = n1z*bnx - n1x*bnz;
        const float m1z = n1x*bny - n1y*bnx;
        const float sy = m1x*n2x + m1y*n2y + m1z*n2z;
        const float sx = n1x*n2x + n1y*n2y + n1z*n2z + EPSF;
        const float phi = atan2f(sy, sx);
        const float e_tors = K * (1.0f + cosf(period*phi - x0));

        esum += (nv == 2) ? e_bond : ((nv == 3) ? e_angle : e_tors);
    }

    // wave reduce, one atomic per wave (no extra LDS: we're at exactly 64 KB)
    #pragma unroll
    for (int off = 32; off > 0; off >>= 1) esum += __shfl_down(esum, off, 64);
    if ((tid & 63) == 0 && esum != 0.0f) atomicAdd(&out[pose], esum);
}

// ---------------- fallback (proven 70 us path) if ws too small ----------------
__global__ __launch_bounds__(256) void fb_kernel(const float* __restrict__ coords,
                                                 const float* __restrict__ hv,
                                                 const int4v* __restrict__ atoms,
                                                 const int*   __restrict__ pose,
                                                 const int*   __restrict__ uids,
                                                 float* __restrict__ out, int S) {
    __shared__ float bins[P_POSES];
    if (threadIdx.x < P_POSES) bins[threadIdx.x] = 0.0f;
    __syncthreads();
    const int s = blockIdx.x * blockDim.x + threadIdx.x;
    if (s < S) {
        const int4v a = atoms[s];
        const int   p = pose[s];
        const bool v0 = a.x >= 0, v1 = a.y >= 0, v2 = a.z >= 0, v3 = a.w >= 0;
        const int  i0 = v0 ? a.x : 0, i1 = v1 ? a.y : 0, i2 = v2 ? a.z : 0, i3 = v3 ? a.w : 0;
        const int  nv = (int)v0 + (int)v1 + (int)v2 + (int)v3;
        const int* urow = uids + p * A_ATOMS;
        unsigned int key = (v0?(unsigned)urow[i0]:0u) + (v1?(unsigned)urow[i1]:0u)
                         + (v2?(unsigned)urow[i2]:0u) + (v3?(unsigned)urow[i3]:0u);
        key &= (unsigned)(T_HASH - 1);
        const float K = hv[3*key], x0 = hv[3*key+1], period = hv[3*key+2];
        const float* crow = coords + (size_t)p * (A_ATOMS * 3);
        const float p0x=crow[i0*3],p0y=crow[i0*3+1],p0z=crow[i0*3+2];
        const float p1x=crow[i1*3],p1y=crow[i1*3+1],p1z=crow[i1*3+2];
        const float p2x=crow[i2*3],p2y=crow[i2*3+1],p2z=crow[i2*3+2];
        const float p3x=crow[i3*3],p3y=crow[i3*3+1],p3z=crow[i3*3+2];
        const float dbx=p1x-p0x,dby=p1y-p0y,dbz=p1z-p0z;
        const float d=sqrtf(dbx*dbx+dby*dby+dbz*dbz+EPSF);
        const float e_bond=K*(d-x0)*(d-x0);
        const float ux=-dbx,uy=-dby,uz=-dbz;
        const float vx=p2x-p1x,vy=p2y-p1y,vz=p2z-p1z;
        float cosang=(ux*vx+uy*vy+uz*vz)/(sqrtf(ux*ux+uy*uy+uz*uz+EPSF)*sqrtf(vx*vx+vy*vy+vz*vz+EPSF));
        cosang=fminf(fmaxf(cosang,-0.999999f),0.999999f);
        const float th=acosf(cosang);
        const float e_angle=K*(th-x0)*(th-x0);
        const float b3x=p3x-p2x,b3y=p3y-p2y,b3z=p3z-p2z;
        const float n1x=dby*vz-dbz*vy,n1y=dbz*vx-dbx*vz,n1z=dbx*vy-dby*vx;
        const float n2x=vy*b3z-vz*b3y,n2y=vz*b3x-vx*b3z,n2z=vx*b3y-vy*b3x;
        const float bi=1.0f/sqrtf(vx*vx+vy*vy+vz*vz+EPSF);
        const float bnx=vx*bi,bny=vy*bi,bnz=vz*bi;
        const float m1x=n1y*bnz-n1z*bny,m1y=n1z*bnx-n1x*bnz,m1z=n1x*bny-n1y*bnx;
        const float sy=m1x*n2x+m1y*n2y+m1z*n2z;
        const float sx=n1x*n2x+n1y*n2y+n1z*n2z+EPSF;
        const float e_tors=K*(1.0f+cosf(period*atan2f(sy,sx)-x0));
        atomicAdd(&bins[p],(nv==2)?e_bond:((nv==3)?e_angle:e_tors));
    }
    __syncthreads();
    if (threadIdx.x < P_POSES) {
        const float b = bins[threadIdx.x];
        if (b != 0.0f) atomicAdd(&out[threadIdx.x], b);
    }
}

extern "C" void kernel_launch(void* const* d_in, const int* in_sizes, int n_in,
                              void* d_out, int out_size, void* d_ws, size_t ws_size,
                              hipStream_t stream) {
    const float* coords = (const float*)d_in[0];
    const float* hv     = (const float*)d_in[1];
    const int4v* atoms  = (const int4v*)d_in[2];
    const int*   pose   = (const int*)d_in[3];
    const int*   uids   = (const int*)d_in[4];
    float* out = (float*)d_out;
    const int S = in_sizes[3];

    const size_t needed = 1024 + (size_t)S * 16;
    hipMemsetAsync(out, 0, P_POSES * sizeof(float), stream);

    if (ws_size < needed) {
        fb_kernel<<<(S + 255) / 256, 256, 0, stream>>>(coords, hv, atoms, pose, uids, out, S);
        return;
    }

    int* counts  = (int*)d_ws;          // [32]
    int* start   = counts + 32;         // [33]
    int* cursor  = counts + 96;         // [32]
    int4v* sorted = (int4v*)((char*)d_ws + 1024);

    hipMemsetAsync(counts, 0, P_POSES * sizeof(int), stream);
    k1_hist<<<1024, 256, 0, stream>>>(pose, counts, S);
    k2_scan<<<1, 64, 0, stream>>>(counts, start, cursor);
    k3_scatter<<<(S + CHUNK - 1) / CHUNK, 256, 0, stream>>>(pose, atoms, cursor, sorted, S);
    k4_main<<<P_POSES * KSUB, 256, 0, stream>>>(coords, hv, uids, start, sorted, out);
}